// Round 1
// baseline (159.238 us; speedup 1.0000x reference)
//
#include <hip/hip_runtime.h>
#include <math.h>

// Chamfer loss: B=4, N=M=8192, D=3, fp32.
// d1[b,n] = min_m ||p[b,n]-g[b,m]||^2 ; d2[b,m] = min_n ...
// loss = 0.5*(mean(sqrt(d1)) + mean(sqrt(d2)))

#define THREADS 256
#define IT 4                  // pred points per thread (register blocked)
#define PB (THREADS * IT)     // 1024 points per block
#define MC 1024               // gt points staged in LDS per block

__global__ void init_min_kernel(unsigned* __restrict__ mins, int n) {
    int i = blockIdx.x * blockDim.x + threadIdx.x;
    if (i < n) mins[i] = 0x7F800000u;  // +inf bits
}

// grid: (N/PB, M/MC, 2*B).  z < B: pred->gt direction, batch z.
//                           z >= B: gt->pred direction, batch z-B.
__global__ __launch_bounds__(THREADS) void chamfer_min_kernel(
    const float* __restrict__ P, const float* __restrict__ G,
    unsigned* __restrict__ mins1, unsigned* __restrict__ mins2,
    int N, int M) {
    int z = blockIdx.z;
    int B = gridDim.z >> 1;
    const float* src;   // points we own per-thread (rows)
    const float* oth;   // points we stream through LDS (cols)
    unsigned* out;
    int b;
    if (z < B) { b = z;     src = P; oth = G; out = mins1; }
    else       { b = z - B; src = G; oth = P; out = mins2; }
    // N == M == 8192 so row/col extents are interchangeable here.
    const float* Sb = src + (size_t)b * N * 3;
    const float* Ob = oth + (size_t)b * M * 3;

    int row0 = blockIdx.x * PB;
    int col0 = blockIdx.y * MC;

    __shared__ float4 g_lds[MC];
    for (int j = threadIdx.x; j < MC; j += THREADS) {
        const float* gp = Ob + (size_t)(col0 + j) * 3;
        g_lds[j] = make_float4(gp[0], gp[1], gp[2], 0.0f);
    }
    __syncthreads();

    float px[IT], py[IT], pz[IT], mn[IT];
#pragma unroll
    for (int i = 0; i < IT; ++i) {
        int r = row0 + threadIdx.x + i * THREADS;
        const float* pp = Sb + (size_t)r * 3;
        px[i] = pp[0]; py[i] = pp[1]; pz[i] = pp[2];
        mn[i] = INFINITY;
    }

#pragma unroll 4
    for (int j = 0; j < MC; ++j) {
        float4 g = g_lds[j];
#pragma unroll
        for (int i = 0; i < IT; ++i) {
            float dx = px[i] - g.x;
            float dy = py[i] - g.y;
            float dz = pz[i] - g.z;
            float d = fmaf(dx, dx, fmaf(dy, dy, dz * dz));
            mn[i] = fminf(mn[i], d);
        }
    }

#pragma unroll
    for (int i = 0; i < IT; ++i) {
        int r = row0 + threadIdx.x + i * THREADS;
        // d >= 0 so uint bit compare == float compare
        atomicMin(&out[(size_t)b * N + r], __float_as_uint(mn[i]));
    }
}

__global__ __launch_bounds__(256) void chamfer_reduce_kernel(
    const unsigned* __restrict__ mins, int n1, int n2,
    float* __restrict__ out) {
    const unsigned* m1 = mins;
    const unsigned* m2 = mins + n1;
    float w1 = 0.5f / (float)n1;
    float w2 = 0.5f / (float)n2;
    float acc = 0.0f;
    for (int i = threadIdx.x; i < n1; i += blockDim.x)
        acc += w1 * sqrtf(__uint_as_float(m1[i]));
    for (int i = threadIdx.x; i < n2; i += blockDim.x)
        acc += w2 * sqrtf(__uint_as_float(m2[i]));

    // wave64 reduce
#pragma unroll
    for (int off = 32; off > 0; off >>= 1)
        acc += __shfl_down(acc, off, 64);

    __shared__ float sdata[4];
    int lane = threadIdx.x & 63;
    int wave = threadIdx.x >> 6;
    if (lane == 0) sdata[wave] = acc;
    __syncthreads();
    if (threadIdx.x == 0) {
        float s = sdata[0] + sdata[1] + sdata[2] + sdata[3];
        out[0] = s;
    }
}

extern "C" void kernel_launch(void* const* d_in, const int* in_sizes, int n_in,
                              void* d_out, int out_size, void* d_ws, size_t ws_size,
                              hipStream_t stream) {
    const float* P = (const float*)d_in[0];
    const float* G = (const float*)d_in[1];
    const int B = 4;
    const int N = in_sizes[0] / (B * 3);   // 8192
    const int M = in_sizes[1] / (B * 3);   // 8192

    unsigned* mins = (unsigned*)d_ws;      // [B*N] dir1 then [B*M] dir2
    float* out = (float*)d_out;

    int totmins = B * (N + M);
    init_min_kernel<<<(totmins + 255) / 256, 256, 0, stream>>>(mins, totmins);

    dim3 grid(N / PB, M / MC, 2 * B);      // (8, 8, 8) = 512 blocks
    chamfer_min_kernel<<<grid, THREADS, 0, stream>>>(
        P, G, mins, mins + (size_t)B * N, N, M);

    chamfer_reduce_kernel<<<1, 256, 0, stream>>>(mins, B * N, B * M, out);
}

// Round 2
// 57.688 us; speedup vs baseline: 2.7604x; 2.7604x over previous
//
#include <hip/hip_runtime.h>
#include <math.h>

// Chamfer loss: B=4, N=M=8192, D=3, fp32.
// d1[b,n] = min_m ||p[b,n]-g[b,m]||^2 ; d2[b,m] = min_n ...
// loss = 0.5*(mean(sqrt(d1)) + mean(sqrt(d2)))
//
// Inner loop uses the reference's expanded form:
//   d = pn + (gn - 2 p.g)  ->  per pair: 3 FMA + 1 MIN (4 VALU ops)
// ws layout: [B*N + B*M] uint32 min-bits, then [RB1] float partials.

#define THREADS 256
#define IT 4                  // points per thread (register blocked)
#define PB (THREADS * IT)     // 1024 points per block
#define MC 1024               // opposite-set points staged in LDS per block
#define RB1 64                // stage-1 reduce blocks

__global__ void init_min_kernel(unsigned* __restrict__ mins, int n) {
    int i = blockIdx.x * blockDim.x + threadIdx.x;
    if (i < n) mins[i] = 0x7F800000u;  // +inf bits
}

// grid: (N/PB, M/MC, 2*B).  z < B: pred->gt direction; z >= B: gt->pred.
__global__ __launch_bounds__(THREADS) void chamfer_min_kernel(
    const float* __restrict__ P, const float* __restrict__ G,
    unsigned* __restrict__ mins1, unsigned* __restrict__ mins2,
    int N, int M) {
    int z = blockIdx.z;
    int B = gridDim.z >> 1;
    const float* src; const float* oth; unsigned* out; int b;
    if (z < B) { b = z;     src = P; oth = G; out = mins1; }
    else       { b = z - B; src = G; oth = P; out = mins2; }
    const float* Sb = src + (size_t)b * N * 3;
    const float* Ob = oth + (size_t)b * M * 3;

    int row0 = blockIdx.x * PB;
    int col0 = blockIdx.y * MC;

    // (gx, gy, gz, gn) per staged point
    __shared__ float4 g_lds[MC];
    for (int j = threadIdx.x; j < MC; j += THREADS) {
        const float* gp = Ob + (size_t)(col0 + j) * 3;
        float gx = gp[0], gy = gp[1], gz = gp[2];
        float gn = fmaf(gx, gx, fmaf(gy, gy, gz * gz));
        g_lds[j] = make_float4(gx, gy, gz, gn);
    }
    __syncthreads();

    float a[IT], c2[IT], c3[IT], pn[IT], mn[IT];
#pragma unroll
    for (int i = 0; i < IT; ++i) {
        int r = row0 + threadIdx.x + i * THREADS;
        const float* pp = Sb + (size_t)r * 3;
        float px = pp[0], py = pp[1], pz = pp[2];
        a[i]  = -2.0f * px;
        c2[i] = -2.0f * py;
        c3[i] = -2.0f * pz;
        pn[i] = fmaf(px, px, fmaf(py, py, pz * pz));
        mn[i] = INFINITY;
    }

#pragma unroll 4
    for (int j = 0; j < MC; ++j) {
        float4 g = g_lds[j];
#pragma unroll
        for (int i = 0; i < IT; ++i) {
            // gn - 2 p.g  (pn added after the min; min is monotone-shift-invariant)
            float t = fmaf(g.x, a[i], fmaf(g.y, c2[i], fmaf(g.z, c3[i], g.w)));
            mn[i] = fminf(mn[i], t);
        }
    }

#pragma unroll
    for (int i = 0; i < IT; ++i) {
        int r = row0 + threadIdx.x + i * THREADS;
        float d = fmaxf(pn[i] + mn[i], 0.0f);   // >= 0 so uint order == float order
        atomicMin(&out[(size_t)b * N + r], __float_as_uint(d));
    }
}

// Stage 1: RB1 blocks, each sums a contiguous slice of the 2*B*N mins.
__global__ __launch_bounds__(256) void reduce1_kernel(
    const unsigned* __restrict__ mins, int n1, int n2,
    float* __restrict__ partials) {
    int total = n1 + n2;
    int per_block = total / RB1;               // 65536/64 = 1024
    int base = blockIdx.x * per_block;
    float w1 = 0.5f / (float)n1;
    float w2 = 0.5f / (float)n2;

    float acc = 0.0f;
    for (int i = threadIdx.x; i < per_block; i += blockDim.x) {
        int idx = base + i;
        float v = __uint_as_float(mins[idx]);
        float w = (idx < n1) ? w1 : w2;
        acc += w * sqrtf(v);
    }
#pragma unroll
    for (int off = 32; off > 0; off >>= 1)
        acc += __shfl_down(acc, off, 64);

    __shared__ float sdata[4];
    int lane = threadIdx.x & 63;
    int wave = threadIdx.x >> 6;
    if (lane == 0) sdata[wave] = acc;
    __syncthreads();
    if (threadIdx.x == 0)
        partials[blockIdx.x] = sdata[0] + sdata[1] + sdata[2] + sdata[3];
}

// Stage 2: one wave sums the RB1 partials (fixed order -> deterministic).
__global__ __launch_bounds__(64) void reduce2_kernel(
    const float* __restrict__ partials, float* __restrict__ out) {
    float acc = (threadIdx.x < RB1) ? partials[threadIdx.x] : 0.0f;
#pragma unroll
    for (int off = 32; off > 0; off >>= 1)
        acc += __shfl_down(acc, off, 64);
    if (threadIdx.x == 0) out[0] = acc;
}

extern "C" void kernel_launch(void* const* d_in, const int* in_sizes, int n_in,
                              void* d_out, int out_size, void* d_ws, size_t ws_size,
                              hipStream_t stream) {
    const float* P = (const float*)d_in[0];
    const float* G = (const float*)d_in[1];
    const int B = 4;
    const int N = in_sizes[0] / (B * 3);   // 8192
    const int M = in_sizes[1] / (B * 3);   // 8192

    unsigned* mins = (unsigned*)d_ws;                  // B*(N+M) uints
    float* partials = (float*)(mins + (size_t)B * (N + M));
    float* out = (float*)d_out;

    int totmins = B * (N + M);
    init_min_kernel<<<(totmins + 255) / 256, 256, 0, stream>>>(mins, totmins);

    dim3 grid(N / PB, M / MC, 2 * B);      // (8, 8, 8) = 512 blocks
    chamfer_min_kernel<<<grid, THREADS, 0, stream>>>(
        P, G, mins, mins + (size_t)B * N, N, M);

    reduce1_kernel<<<RB1, 256, 0, stream>>>(mins, B * N, B * M, partials);
    reduce2_kernel<<<1, 64, 0, stream>>>(partials, out);
}

// Round 3
// 52.250 us; speedup vs baseline: 3.0476x; 1.1041x over previous
//
#include <hip/hip_runtime.h>
#include <math.h>

// Chamfer loss: B=4, N=M=8192, D=3, fp32.
// d = pn + (gn - 2 p.g); per column-PAIR per row: 6 FMA + 1 v_min3 (3.5 ops/pair).
// IT=8 rows/thread so one broadcast ds_read_b128 feeds 8 pairs/lane.
// ws: [B*(N+M)] uint32 min-bits, then [RB1] float partials.

#define THREADS 256
#define IT 8                  // rows per thread (register blocked)
#define PB (THREADS * IT)     // 2048 rows per block
#define MC 512                // columns staged in LDS per block
#define RB1 64                // stage-1 reduce blocks

__global__ void init_min_kernel(unsigned* __restrict__ mins, int n) {
    int i = blockIdx.x * blockDim.x + threadIdx.x;
    if (i < n) mins[i] = 0x7F800000u;  // +inf bits
}

// grid: (N/PB, M/MC, 2*B).  z < B: pred->gt; z >= B: gt->pred.
__global__ __launch_bounds__(THREADS) void chamfer_min_kernel(
    const float* __restrict__ P, const float* __restrict__ G,
    unsigned* __restrict__ mins1, unsigned* __restrict__ mins2,
    int N, int M) {
    int z = blockIdx.z;
    int B = gridDim.z >> 1;
    const float* src; const float* oth; unsigned* out; int b;
    if (z < B) { b = z;     src = P; oth = G; out = mins1; }
    else       { b = z - B; src = G; oth = P; out = mins2; }
    const float* Sb = src + (size_t)b * N * 3;
    const float* Ob = oth + (size_t)b * M * 3;

    int row0 = blockIdx.x * PB;
    int col0 = blockIdx.y * MC;

    // (gx, gy, gz, gn) per staged column point
    __shared__ float4 g_lds[MC];
    for (int j = threadIdx.x; j < MC; j += THREADS) {
        const float* gp = Ob + (size_t)(col0 + j) * 3;
        float gx = gp[0], gy = gp[1], gz = gp[2];
        g_lds[j] = make_float4(gx, gy, gz, fmaf(gx, gx, fmaf(gy, gy, gz * gz)));
    }
    __syncthreads();

    float a1[IT], a2[IT], a3[IT], pn[IT], mn[IT];
#pragma unroll
    for (int i = 0; i < IT; ++i) {
        int r = row0 + threadIdx.x + i * THREADS;
        const float* pp = Sb + (size_t)r * 3;
        float px = pp[0], py = pp[1], pz = pp[2];
        a1[i] = -2.0f * px;
        a2[i] = -2.0f * py;
        a3[i] = -2.0f * pz;
        pn[i] = fmaf(px, px, fmaf(py, py, pz * pz));
        mn[i] = INFINITY;
    }

#pragma unroll 2
    for (int j = 0; j < MC; j += 2) {
        float4 g0 = g_lds[j];
        float4 g1 = g_lds[j + 1];
#pragma unroll
        for (int i = 0; i < IT; ++i) {
            // gn - 2 p.g  (pn added after the min; min is shift-invariant)
            float t0 = fmaf(g0.x, a1[i], fmaf(g0.y, a2[i], fmaf(g0.z, a3[i], g0.w)));
            float t1 = fmaf(g1.x, a1[i], fmaf(g1.y, a2[i], fmaf(g1.z, a3[i], g1.w)));
            mn[i] = fminf(fminf(t0, t1), mn[i]);   // -> v_min3_f32
        }
    }

#pragma unroll
    for (int i = 0; i < IT; ++i) {
        int r = row0 + threadIdx.x + i * THREADS;
        float d = fmaxf(pn[i] + mn[i], 0.0f);   // >= 0 so uint order == float order
        atomicMin(&out[(size_t)b * N + r], __float_as_uint(d));
    }
}

// Stage 1: RB1 blocks, each sums a contiguous slice of the mins.
__global__ __launch_bounds__(256) void reduce1_kernel(
    const unsigned* __restrict__ mins, int n1, int n2,
    float* __restrict__ partials) {
    int total = n1 + n2;
    int per_block = total / RB1;               // 1024
    int base = blockIdx.x * per_block;
    float w1 = 0.5f / (float)n1;
    float w2 = 0.5f / (float)n2;

    float acc = 0.0f;
    for (int i = threadIdx.x; i < per_block; i += blockDim.x) {
        int idx = base + i;
        float v = __uint_as_float(mins[idx]);
        float w = (idx < n1) ? w1 : w2;
        acc += w * sqrtf(v);
    }
#pragma unroll
    for (int off = 32; off > 0; off >>= 1)
        acc += __shfl_down(acc, off, 64);

    __shared__ float sdata[4];
    int lane = threadIdx.x & 63;
    int wave = threadIdx.x >> 6;
    if (lane == 0) sdata[wave] = acc;
    __syncthreads();
    if (threadIdx.x == 0)
        partials[blockIdx.x] = sdata[0] + sdata[1] + sdata[2] + sdata[3];
}

// Stage 2: one wave sums the RB1 partials (fixed order -> deterministic).
__global__ __launch_bounds__(64) void reduce2_kernel(
    const float* __restrict__ partials, float* __restrict__ out) {
    float acc = (threadIdx.x < RB1) ? partials[threadIdx.x] : 0.0f;
#pragma unroll
    for (int off = 32; off > 0; off >>= 1)
        acc += __shfl_down(acc, off, 64);
    if (threadIdx.x == 0) out[0] = acc;
}

extern "C" void kernel_launch(void* const* d_in, const int* in_sizes, int n_in,
                              void* d_out, int out_size, void* d_ws, size_t ws_size,
                              hipStream_t stream) {
    const float* P = (const float*)d_in[0];
    const float* G = (const float*)d_in[1];
    const int B = 4;
    const int N = in_sizes[0] / (B * 3);   // 8192
    const int M = in_sizes[1] / (B * 3);   // 8192

    unsigned* mins = (unsigned*)d_ws;                  // B*(N+M) uints
    float* partials = (float*)(mins + (size_t)B * (N + M));
    float* out = (float*)d_out;

    int totmins = B * (N + M);
    init_min_kernel<<<(totmins + 255) / 256, 256, 0, stream>>>(mins, totmins);

    dim3 grid(N / PB, M / MC, 2 * B);      // (4, 16, 8) = 512 blocks
    chamfer_min_kernel<<<grid, THREADS, 0, stream>>>(
        P, G, mins, mins + (size_t)B * N, N, M);

    reduce1_kernel<<<RB1, 256, 0, stream>>>(mins, B * N, B * M, partials);
    reduce2_kernel<<<1, 64, 0, stream>>>(partials, out);
}